// Round 5
// baseline (313.277 us; speedup 1.0000x reference)
//
#include <hip/hip_runtime.h>
#include <hip/hip_fp16.h>
#include <math.h>

// QFF1: per point n, per freq f: enc[m=s*3+d] = {sin,cos}(p_d * freq_f)
// pos=(enc+1)*39.5; lerp into table qv[f*6+m][cr][q];
// out[n][(f*2+s)*4 + c] = sum_r prod_d lerp(m=s*3+d, cr=c*8+r)
//
// R5 structure: ONE block = 256 points x ALL 6 freqs -> single writer per
// output row -> fully coalesced full-line writes (kills R2/R4's 7x write amp,
// which came from 6 blocks writing 32-B fragments of the same lines into
// non-shared L2s).
//   - prep kernel: qff f32 [T][cr][q] -> ws fp16 [T][q][40] (80-B padded rows,
//     bank-group of 16B chunk jc at row q = (5q+jc)&7, 5 coprime 8), scaled
//     x128 so products can run as v_pk_mul_f16 without denormals.
//   - main: per freq, linear float4 copy ws->LDS (2 barriers), R4-style
//     gather+lerp, packed f16 products, acc[48] in VGPRs (f-loop unrolled,
//     all static indexing), then LDS transpose (52-float stride) -> coalesced
//     float4 row stores.

constexpr int N_POINTS = 131072;
constexpr int NFREQ    = 6;
constexpr int QN       = 80;
constexpr int CRN      = 32;     // NUM_FEATS(4) * NUM_CORRS(8)
constexpr int M_PER_F  = 6;
constexpr int ROW      = 40;              // halves per q-row (80 B)
constexpr int MSTRIDE  = QN * ROW;        // 3200 halves per table
constexpr int TSTRIDE  = CRN * QN;        // 2560 floats per src table
constexpr int FH       = M_PER_F * MSTRIDE;   // 19200 halves per freq in ws
constexpr int NTAB     = NFREQ * M_PER_F;     // 36 tables

constexpr int TB       = 256;             // main-kernel block size
constexpr int DSTRIDE  = 52;              // dump stride in floats (48 + 4 pad)
constexpr int LDS_BYTES = TB * DSTRIDE * 4;   // 53248 >= 38400 table buf

constexpr float SCALE   = 128.0f;
constexpr float UNSCALE = 1.0f / (SCALE * SCALE * SCALE);

// ---------------- prep: transpose + pad + fp16 + x128 ----------------
__global__ __launch_bounds__(256)
void qff1_prep(const float* __restrict__ qff, __half* __restrict__ wsh)
{
    int i = blockIdx.x * 256 + threadIdx.x;        // over 36*2560 src elements
    if (i >= NTAB * TSTRIDE) return;
    int T  = i / TSTRIDE;
    int r  = i - T * TSTRIDE;
    int cr = r / QN;
    int q  = r - cr * QN;
    wsh[T * MSTRIDE + q * ROW + cr] = __float2half(qff[i] * SCALE);
}

// ---------------- main ----------------
__global__ __launch_bounds__(TB, 3)
void qff1_main(const float* __restrict__ points,
               const __half* __restrict__ wsh,
               const float* __restrict__ freqs,
               float* __restrict__ out)
{
    __shared__ __align__(16) unsigned char lds_raw[LDS_BYTES];
    __half* tab  = reinterpret_cast<__half*>(lds_raw);
    float*  dmp  = reinterpret_cast<float*>(lds_raw);

    const int tid = threadIdx.x;
    const int n   = blockIdx.x * TB + tid;

    const float px = points[n * 3 + 0];
    const float py = points[n * 3 + 1];
    const float pz = points[n * 3 + 2];

    float acc[48];

#pragma unroll
    for (int f = 0; f < NFREQ; ++f) {
        __syncthreads();   // previous freq's LDS reads complete before overwrite
        {   // linear fp16 table copy: 2400 float4 per freq
            const float4* src = reinterpret_cast<const float4*>(wsh + f * FH);
            float4* dst = reinterpret_cast<float4*>(lds_raw);
            for (int j = tid; j < FH / 8; j += TB) dst[j] = src[j];
        }
        __syncthreads();

        const float freq = freqs[f];
        float enc[6];
        {
            float s, cc;
            __sincosf(px * freq, &s, &cc); enc[0] = s; enc[3] = cc;
            __sincosf(py * freq, &s, &cc); enc[1] = s; enc[4] = cc;
            __sincosf(pz * freq, &s, &cc); enc[2] = s; enc[5] = cc;
        }

        int b0[6], b1[6];
        __half2 w2[6];
#pragma unroll
        for (int m = 0; m < 6; ++m) {
            float pos = (enc[m] + 1.0f) * (0.5f * (float)(QN - 1));
            float fi  = floorf(pos);
            int i0    = (int)fi;
            i0 = i0 < 0 ? 0 : (i0 > QN - 1 ? QN - 1 : i0);
            int i1 = i0 + 1; if (i1 > QN - 1) i1 = QN - 1;
            w2[m] = __float2half2_rn(pos - (float)i0);
            b0[m] = m * MSTRIDE + i0 * ROW;
            b1[m] = m * MSTRIDE + i1 * ROW;
        }

#pragma unroll
        for (int s = 0; s < 2; ++s) {
#pragma unroll
            for (int jc = 0; jc < 4; ++jc) {   // feature c=jc, ranks 0..7
                __half2 P[3][4];
#pragma unroll
                for (int d = 0; d < 3; ++d) {
                    int m = s * 3 + d;
                    union { float4 v; __half2 h[4]; } A, B;
                    A.v = *(const float4*)&tab[b0[m] + jc * 8];
                    B.v = *(const float4*)&tab[b1[m] + jc * 8];
#pragma unroll
                    for (int kk = 0; kk < 4; ++kk)
                        P[d][kk] = __hfma2(w2[m], __hsub2(B.h[kk], A.h[kk]), A.h[kk]);
                }
                // packed 3-way products (values x128^3: normals, no overflow)
                __half2 pr[4];
#pragma unroll
                for (int kk = 0; kk < 4; ++kk)
                    pr[kk] = __hmul2(__hmul2(P[0][kk], P[1][kk]), P[2][kk]);
                __half2 s0 = __hadd2(pr[0], pr[1]);
                __half2 s1 = __hadd2(pr[2], pr[3]);
                float2 f0 = __half22float2(s0);
                float2 f1 = __half22float2(s1);
                acc[f * 8 + s * 4 + jc] = (f0.x + f0.y) + (f1.x + f1.y);
            }
        }
    }

    // ---- LDS transpose -> coalesced full-line stores
    __syncthreads();   // all table reads done before dump overwrites LDS
#pragma unroll
    for (int c = 0; c < 12; ++c) {
        *(float4*)&dmp[tid * DSTRIDE + c * 4] =
            make_float4(acc[c * 4 + 0] * UNSCALE, acc[c * 4 + 1] * UNSCALE,
                        acc[c * 4 + 2] * UNSCALE, acc[c * 4 + 3] * UNSCALE);
    }
    __syncthreads();

    float4* o4 = reinterpret_cast<float4*>(out) + (size_t)blockIdx.x * (TB * 12);
#pragma unroll
    for (int k = 0; k < 12; ++k) {
        int i = tid + k * TB;          // 0..3071
        int p = i / 12;
        int c = i - p * 12;
        o4[i] = *(const float4*)&dmp[p * DSTRIDE + c * 4];
    }
}

extern "C" void kernel_launch(void* const* d_in, const int* in_sizes, int n_in,
                              void* d_out, int out_size, void* d_ws, size_t ws_size,
                              hipStream_t stream) {
    const float* points = (const float*)d_in[0];   // (131072, 3)
    const float* qff    = (const float*)d_in[1];   // (36, 32, 80, 1)
    const float* freqs  = (const float*)d_in[2];   // (6,)
    float* out  = (float*)d_out;                   // (131072, 48)
    __half* wsh = (__half*)d_ws;                   // 36*3200 halves = 230400 B

    qff1_prep<<<dim3((NTAB * TSTRIDE + 255) / 256), dim3(256), 0, stream>>>(qff, wsh);
    qff1_main<<<dim3(N_POINTS / TB), dim3(TB), 0, stream>>>(points, wsh, freqs, out);
}

// Round 6
// 62.977 us; speedup vs baseline: 4.9745x; 4.9745x over previous
//
#include <hip/hip_runtime.h>
#include <hip/hip_fp16.h>
#include <math.h>

// QFF1 two-pass:
//   prep : qff f32 [T][cr][q] -> ws tables fp16 [T][q][40] (80-B padded rows;
//          bank-group of 16B chunk jc at row q = (5q+jc)&7, 5 coprime 8 =>
//          random gather rows spread over all 8 groups).
//   passA: one block = (512-point chunk, freq). R4's register-lean gather+lerp
//          (VGPR~32). Output: two float4 per thread into PLANE-MAJOR
//          planes[(f*2+s)][n] -> every wave-store is 1 KB contiguous,
//          every line written once by one block. Kills partial-line RMW.
//   passB: block = 256 points; read 12 planes coalesced (b128), LDS transpose
//          (stride 13 float4, 13 mod 8 = 5 coprime 8 -> conflict-free b128
//          on both sides), write full 192-B rows coalesced.
// Fallback (ws too small): self-contained R4-style kernel, direct writes.

constexpr int N_POINTS = 131072;
constexpr int NFREQ    = 6;
constexpr int QN       = 80;
constexpr int CRN      = 32;     // NUM_FEATS(4) * NUM_CORRS(8)
constexpr int M_PER_F  = 6;      // {sin,cos} x 3 dims
constexpr int ROW      = 40;                 // halves per q-row (80 B)
constexpr int MSTRIDE  = QN * ROW;           // 3200 halves per table
constexpr int TSTRIDE  = CRN * QN;           // 2560 floats per src table
constexpr int FH       = M_PER_F * MSTRIDE;  // 19200 halves per freq
constexpr int NTAB     = NFREQ * M_PER_F;    // 36 tables

constexpr int TA     = 512;                  // pass A block (points per chunk)
constexpr int NCHUNK = N_POINTS / TA;        // 256
constexpr int TBB    = 256;                  // pass B block

constexpr size_t PLANE_BYTES = (size_t)12 * N_POINTS * 16;    // 25.17 MB
constexpr size_t TAB_BYTES   = (size_t)NTAB * MSTRIDE * 2;    // 230400 B

// ---------------- prep: transpose + pad + fp16 ----------------
__global__ __launch_bounds__(256)
void qff1_prep(const float* __restrict__ qff, __half* __restrict__ wsh)
{
    int i = blockIdx.x * 256 + threadIdx.x;        // over 36*2560 src elements
    if (i >= NTAB * TSTRIDE) return;
    int T  = i / TSTRIDE;
    int r  = i - T * TSTRIDE;
    int cr = r / QN;
    int q  = r - cr * QN;
    wsh[T * MSTRIDE + q * ROW + cr] = __float2half(qff[i]);
}

// ---------------- shared compute core (R4-proven) ----------------
__device__ __forceinline__ void qff1_core(const __half* tab,
                                          float px, float py, float pz,
                                          float freq, float acc[8])
{
    float enc[6];
    {
        float s, cc;
        __sincosf(px * freq, &s, &cc); enc[0] = s; enc[3] = cc;
        __sincosf(py * freq, &s, &cc); enc[1] = s; enc[4] = cc;
        __sincosf(pz * freq, &s, &cc); enc[2] = s; enc[5] = cc;
    }
    int b0[6], b1[6];
    __half2 w2[6];
#pragma unroll
    for (int m = 0; m < 6; ++m) {
        float pos = (enc[m] + 1.0f) * (0.5f * (float)(QN - 1));
        float fi  = floorf(pos);
        int i0    = (int)fi;
        i0 = i0 < 0 ? 0 : (i0 > QN - 1 ? QN - 1 : i0);
        int i1 = i0 + 1; if (i1 > QN - 1) i1 = QN - 1;
        w2[m] = __float2half2_rn(pos - (float)i0);
        b0[m] = m * MSTRIDE + i0 * ROW;
        b1[m] = m * MSTRIDE + i1 * ROW;
    }
#pragma unroll
    for (int s = 0; s < 2; ++s) {
#pragma unroll
        for (int jc = 0; jc < 4; ++jc) {   // feature c=jc, ranks 0..7
            __half2 Lv[3][4];
#pragma unroll
            for (int d = 0; d < 3; ++d) {
                int m = s * 3 + d;
                union { float4 v; __half2 h[4]; } A, B;
                A.v = *(const float4*)&tab[b0[m] + jc * 8];
                B.v = *(const float4*)&tab[b1[m] + jc * 8];
#pragma unroll
                for (int kk = 0; kk < 4; ++kk)
                    Lv[d][kk] = __hfma2(w2[m], __hsub2(B.h[kk], A.h[kk]), A.h[kk]);
            }
            float a = 0.0f;
#pragma unroll
            for (int kk = 0; kk < 4; ++kk) {
                float2 f0 = __half22float2(Lv[0][kk]);
                float2 f1 = __half22float2(Lv[1][kk]);
                float2 f2 = __half22float2(Lv[2][kk]);
                a += f0.x * f1.x * f2.x + f0.y * f1.y * f2.y;
            }
            acc[s * 4 + jc] = a;
        }
    }
}

// ---------------- pass A: compute -> plane-major float4 ----------------
__global__ __launch_bounds__(TA, 8)
void qff1_passA(const float* __restrict__ points,
                const __half* __restrict__ wsh,
                const float* __restrict__ freqs,
                float4* __restrict__ planes)
{
    __shared__ __align__(16) __half tab[FH];   // 38400 B

    const int tid   = threadIdx.x;
    const int chunk = blockIdx.x;
    const int f     = blockIdx.y;

    {   // linear fp16 table copy: 2400 float4
        const float4* src = reinterpret_cast<const float4*>(wsh + (size_t)f * FH);
        float4* dst = reinterpret_cast<float4*>(tab);
        for (int j = tid; j < FH / 8; j += TA) dst[j] = src[j];
    }
    __syncthreads();

    const int n = chunk * TA + tid;
    const float px = points[n * 3 + 0];
    const float py = points[n * 3 + 1];
    const float pz = points[n * 3 + 2];

    float acc[8];
    qff1_core(tab, px, py, pz, freqs[f], acc);

    planes[(size_t)(f * 2 + 0) * N_POINTS + n] =
        make_float4(acc[0], acc[1], acc[2], acc[3]);
    planes[(size_t)(f * 2 + 1) * N_POINTS + n] =
        make_float4(acc[4], acc[5], acc[6], acc[7]);
}

// ---------------- pass B: plane-major -> row-major ----------------
__global__ __launch_bounds__(TBB, 3)
void qff1_passB(const float4* __restrict__ planes, float4* __restrict__ out4)
{
    __shared__ __align__(16) float4 dmp[TBB * 13];   // 53248 B

    const int tid = threadIdx.x;
    const int n0  = blockIdx.x * TBB;

#pragma unroll
    for (int fs = 0; fs < 12; ++fs)
        dmp[tid * 13 + fs] = planes[(size_t)fs * N_POINTS + n0 + tid];
    __syncthreads();

    const size_t base = (size_t)n0 * 12;
#pragma unroll
    for (int k = 0; k < 12; ++k) {
        int i  = tid + k * TBB;
        int p  = i / 12;
        int fs = i - p * 12;
        out4[base + i] = dmp[p * 13 + fs];
    }
}

// ---------------- fallback: self-contained direct-write (R4) ----------------
__global__ __launch_bounds__(TA, 8)
void qff1_fallback(const float* __restrict__ points,
                   const float* __restrict__ qff,
                   const float* __restrict__ freqs,
                   float* __restrict__ out)
{
    __shared__ __align__(16) __half tab[FH];
    const int tid = threadIdx.x;
    const int f   = blockIdx.y;

    const float* tsrc = qff + (size_t)f * (M_PER_F * CRN * QN);
    __half2* lds2 = reinterpret_cast<__half2*>(tab);
    for (int idx = tid; idx < M_PER_F * QN * (CRN / 2); idx += TA) {
        int m   = idx / (QN * CRN / 2);
        int rem = idx - m * (QN * CRN / 2);
        int q   = rem >> 4;
        int cr2 = rem & 15;
        float v0 = tsrc[m * (CRN * QN) + (2 * cr2    ) * QN + q];
        float v1 = tsrc[m * (CRN * QN) + (2 * cr2 + 1) * QN + q];
        lds2[m * (MSTRIDE / 2) + q * (ROW / 2) + cr2] = __floats2half2_rn(v0, v1);
    }
    __syncthreads();

    const int n = blockIdx.x * TA + tid;
    float acc[8];
    qff1_core(tab, points[n * 3], points[n * 3 + 1], points[n * 3 + 2],
              freqs[f], acc);

    float4* o = (float4*)(out + (size_t)n * 48 + f * 8);
    o[0] = make_float4(acc[0], acc[1], acc[2], acc[3]);
    o[1] = make_float4(acc[4], acc[5], acc[6], acc[7]);
}

extern "C" void kernel_launch(void* const* d_in, const int* in_sizes, int n_in,
                              void* d_out, int out_size, void* d_ws, size_t ws_size,
                              hipStream_t stream) {
    const float* points = (const float*)d_in[0];   // (131072, 3)
    const float* qff    = (const float*)d_in[1];   // (36, 32, 80, 1)
    const float* freqs  = (const float*)d_in[2];   // (6,)
    float* out = (float*)d_out;                    // (131072, 48)

    if (ws_size >= PLANE_BYTES + TAB_BYTES) {
        float4* planes = (float4*)d_ws;
        __half* wsh    = (__half*)((char*)d_ws + PLANE_BYTES);
        qff1_prep<<<dim3((NTAB * TSTRIDE + 255) / 256), dim3(256), 0, stream>>>(qff, wsh);
        qff1_passA<<<dim3(NCHUNK, NFREQ), dim3(TA), 0, stream>>>(points, wsh, freqs, planes);
        qff1_passB<<<dim3(N_POINTS / TBB), dim3(TBB), 0, stream>>>(planes, (float4*)out);
    } else {
        qff1_fallback<<<dim3(NCHUNK, NFREQ), dim3(TA), 0, stream>>>(points, qff, freqs, out);
    }
}

// Round 7
// 46.592 us; speedup vs baseline: 6.7238x; 1.3517x over previous
//
#include <hip/hip_runtime.h>
#include <hip/hip_fp16.h>
#include <math.h>

// QFF1 single-pass main + tiny prep.
//   prep : qff f32 [T][cr][q] -> ws fp16 [T][q][40] (80-B padded rows; bank
//          group of 16B chunk jc at row q = (5q+jc)&7, 5 coprime 8 => random
//          gather rows spread across all 8 groups).
//   main : one block = 512 points x ALL 6 freqs. Per-freq acc[8] in registers
//          (register-lean, no spill), all 48 outputs aggregated in an LDS
//          out-stage (stride 13 float4 => conflict-free writes), then ONE
//          contiguous 384-KiB coalesced nontemporal store per block.
//          -> every HBM line written once, by one block (kills R2-R6 write amp
//          and, via nt stores, the L2 table thrash seen in R6 passA).
//   Tables double-buffered through registers (T14 issue-early/write-late).

constexpr int N_POINTS = 131072;
constexpr int NFREQ    = 6;
constexpr int QN       = 80;
constexpr int CRN      = 32;     // NUM_FEATS(4) * NUM_CORRS(8)
constexpr int M_PER_F  = 6;      // {sin,cos} x 3 dims
constexpr int ROW      = 40;                 // halves per q-row (80 B)
constexpr int MSTRIDE  = QN * ROW;           // 3200 halves per table
constexpr int TSTRIDE  = CRN * QN;           // 2560 floats per src table
constexpr int FH       = M_PER_F * MSTRIDE;  // 19200 halves per freq
constexpr int NTAB     = NFREQ * M_PER_F;    // 36 tables
constexpr int FH4      = FH / 8;             // 2400 float4 per freq table

constexpr int TB     = 512;                  // main block = points per block
constexpr int NBLK   = N_POINTS / TB;        // 256
constexpr size_t TAB_BYTES = (size_t)NTAB * MSTRIDE * 2;   // 230400 B

typedef float f32x4 __attribute__((ext_vector_type(4)));

// ---------------- prep: transpose + pad + fp16 ----------------
__global__ __launch_bounds__(256)
void qff1_prep(const float* __restrict__ qff, __half* __restrict__ wsh)
{
    int i = blockIdx.x * 256 + threadIdx.x;        // over 36*2560 src elements
    if (i >= NTAB * TSTRIDE) return;
    int T  = i / TSTRIDE;
    int r  = i - T * TSTRIDE;
    int cr = r / QN;
    int q  = r - cr * QN;
    wsh[T * MSTRIDE + q * ROW + cr] = __float2half(qff[i]);
}

// ---------------- register-lean per-freq core (R4-proven) ----------------
__device__ __forceinline__ void qff1_core(const __half* tab,
                                          float px, float py, float pz,
                                          float freq, float acc[8])
{
    float enc[6];
    {
        float s, cc;
        __sincosf(px * freq, &s, &cc); enc[0] = s; enc[3] = cc;
        __sincosf(py * freq, &s, &cc); enc[1] = s; enc[4] = cc;
        __sincosf(pz * freq, &s, &cc); enc[2] = s; enc[5] = cc;
    }
    int b0[6], b1[6];
    __half2 w2[6];
#pragma unroll
    for (int m = 0; m < 6; ++m) {
        float pos = (enc[m] + 1.0f) * (0.5f * (float)(QN - 1));
        float fi  = floorf(pos);
        int i0    = (int)fi;
        i0 = i0 < 0 ? 0 : (i0 > QN - 1 ? QN - 1 : i0);
        int i1 = i0 + 1; if (i1 > QN - 1) i1 = QN - 1;
        w2[m] = __float2half2_rn(pos - (float)i0);
        b0[m] = m * MSTRIDE + i0 * ROW;
        b1[m] = m * MSTRIDE + i1 * ROW;
    }
#pragma unroll
    for (int s = 0; s < 2; ++s) {
#pragma unroll
        for (int jc = 0; jc < 4; ++jc) {   // feature c=jc, ranks 0..7
            __half2 Lv[3][4];
#pragma unroll
            for (int d = 0; d < 3; ++d) {
                int m = s * 3 + d;
                union { float4 v; __half2 h[4]; } A, B;
                A.v = *(const float4*)&tab[b0[m] + jc * 8];
                B.v = *(const float4*)&tab[b1[m] + jc * 8];
#pragma unroll
                for (int kk = 0; kk < 4; ++kk)
                    Lv[d][kk] = __hfma2(w2[m], __hsub2(B.h[kk], A.h[kk]), A.h[kk]);
            }
            float a = 0.0f;
#pragma unroll
            for (int kk = 0; kk < 4; ++kk) {
                float2 f0 = __half22float2(Lv[0][kk]);
                float2 f1 = __half22float2(Lv[1][kk]);
                float2 f2 = __half22float2(Lv[2][kk]);
                a += f0.x * f1.x * f2.x + f0.y * f1.y * f2.y;
            }
            acc[s * 4 + jc] = a;
        }
    }
}

// ---------------- main ----------------
__global__ __launch_bounds__(TB, 2)
void qff1_main(const float* __restrict__ points,
               const __half* __restrict__ wsh,
               const float* __restrict__ freqs,
               float4* __restrict__ out4)
{
    __shared__ __align__(16) __half  tab[FH];        // 38400 B
    __shared__ __align__(16) float4  dmp[TB * 13];   // 106496 B  (stride 13)

    const int tid = threadIdx.x;
    const int n   = blockIdx.x * TB + tid;

    const float px = points[n * 3 + 0];
    const float py = points[n * 3 + 1];
    const float pz = points[n * 3 + 2];

    // prologue: stage table f=0 (linear float4 copy, conflict-free)
    {
        const float4* src = reinterpret_cast<const float4*>(wsh);
        float4* dst = reinterpret_cast<float4*>(tab);
#pragma unroll
        for (int k = 0; k < 5; ++k) {
            int j = tid + k * TB;
            if (j < FH4) dst[j] = src[j];
        }
    }
    __syncthreads();

    float4 sv[5];

#pragma unroll
    for (int f = 0; f < NFREQ; ++f) {
        // T14 issue-early: next table's global loads in flight during compute
        if (f + 1 < NFREQ) {
            const float4* src = reinterpret_cast<const float4*>(wsh + (size_t)(f + 1) * FH);
#pragma unroll
            for (int k = 0; k < 5; ++k) {
                int j = tid + k * TB;
                if (j < FH4) sv[k] = src[j];
            }
        }

        float acc[8];
        qff1_core(tab, px, py, pz, freqs[f], acc);

        dmp[tid * 13 + f * 2 + 0] = make_float4(acc[0], acc[1], acc[2], acc[3]);
        dmp[tid * 13 + f * 2 + 1] = make_float4(acc[4], acc[5], acc[6], acc[7]);

        __syncthreads();   // table reads + dmp writes of this freq complete

        if (f + 1 < NFREQ) {   // write-late: install next table
            float4* dst = reinterpret_cast<float4*>(tab);
#pragma unroll
            for (int k = 0; k < 5; ++k) {
                int j = tid + k * TB;
                if (j < FH4) dst[j] = sv[k];
            }
            __syncthreads();
        }
    }

    // epilogue: one contiguous 384-KiB coalesced store per block.
    // nontemporal: don't let the output stream evict the L2-hot tables.
    const size_t base = (size_t)blockIdx.x * (TB * 12);
#pragma unroll
    for (int k = 0; k < 12; ++k) {
        int i = tid + k * TB;
        int p = i / 12;
        int c = i - p * 12;
        float4 v = dmp[p * 13 + c];
        __builtin_nontemporal_store(*(const f32x4*)&v, (f32x4*)&out4[base + i]);
    }
}

// ---------------- fallback (ws too small): R4-style direct ----------------
__global__ __launch_bounds__(TB, 8)
void qff1_fallback(const float* __restrict__ points,
                   const float* __restrict__ qff,
                   const float* __restrict__ freqs,
                   float* __restrict__ out)
{
    __shared__ __align__(16) __half tab[FH];
    const int tid = threadIdx.x;
    const int f   = blockIdx.y;

    const float* tsrc = qff + (size_t)f * (M_PER_F * CRN * QN);
    __half2* lds2 = reinterpret_cast<__half2*>(tab);
    for (int idx = tid; idx < M_PER_F * QN * (CRN / 2); idx += TB) {
        int m   = idx / (QN * CRN / 2);
        int rem = idx - m * (QN * CRN / 2);
        int q   = rem >> 4;
        int cr2 = rem & 15;
        float v0 = tsrc[m * (CRN * QN) + (2 * cr2    ) * QN + q];
        float v1 = tsrc[m * (CRN * QN) + (2 * cr2 + 1) * QN + q];
        lds2[m * (MSTRIDE / 2) + q * (ROW / 2) + cr2] = __floats2half2_rn(v0, v1);
    }
    __syncthreads();

    const int n = blockIdx.x * TB + tid;
    float acc[8];
    qff1_core(tab, points[n * 3], points[n * 3 + 1], points[n * 3 + 2],
              freqs[f], acc);

    float4* o = (float4*)(out + (size_t)n * 48 + f * 8);
    o[0] = make_float4(acc[0], acc[1], acc[2], acc[3]);
    o[1] = make_float4(acc[4], acc[5], acc[6], acc[7]);
}

extern "C" void kernel_launch(void* const* d_in, const int* in_sizes, int n_in,
                              void* d_out, int out_size, void* d_ws, size_t ws_size,
                              hipStream_t stream) {
    const float* points = (const float*)d_in[0];   // (131072, 3)
    const float* qff    = (const float*)d_in[1];   // (36, 32, 80, 1)
    const float* freqs  = (const float*)d_in[2];   // (6,)
    float* out = (float*)d_out;                    // (131072, 48)

    if (ws_size >= TAB_BYTES) {
        __half* wsh = (__half*)d_ws;
        qff1_prep<<<dim3((NTAB * TSTRIDE + 255) / 256), dim3(256), 0, stream>>>(qff, wsh);
        qff1_main<<<dim3(NBLK), dim3(TB), 0, stream>>>(points, wsh, freqs, (float4*)out);
    } else {
        qff1_fallback<<<dim3(NBLK, NFREQ), dim3(TB), 0, stream>>>(points, qff, freqs, out);
    }
}